// Round 1
// baseline (3469.520 us; speedup 1.0000x reference)
//
#include <hip/hip_runtime.h>

#define NN 80000
#define NE 1280000
#define F  64

// ---------------------------------------------------------------------------
// edge_index dtype sniffer: reference says int64, harness says int32.
// If the buffer is little-endian int64 with values < 2^31, every odd 32-bit
// word of the first 1000 elements is 0. For int32 data those words are random
// node ids (P(all zero) ~ (1/80000)^1000 ~ 0). Result goes to a device flag.
// ---------------------------------------------------------------------------
__global__ void detect_idx64(const int* __restrict__ idx, int* __restrict__ flag) {
    int z = 1;
    for (int i = 0; i < 1000; ++i) {
        if (idx[2 * i + 1] != 0) { z = 0; break; }
    }
    *flag = z;
}

__device__ __forceinline__ int ld_src(const int* __restrict__ idx, int e, int is64) {
    return is64 ? idx[2 * e] : idx[e];
}
__device__ __forceinline__ int ld_dst(const int* __restrict__ idx, int e, int is64) {
    return is64 ? idx[2 * NE + 2 * e] : idx[NE + e];
}

// deg[d] += 1 for each edge (self-loop +1 folded into dinv_kernel)
__global__ void deg_kernel(const int* __restrict__ idx, const int* __restrict__ flag,
                           int* __restrict__ deg) {
    int e = blockIdx.x * blockDim.x + threadIdx.x;
    if (e >= NE) return;
    int is64 = *flag;
    atomicAdd(&deg[ld_dst(idx, e, is64)], 1);
}

__global__ void dinv_kernel(const int* __restrict__ deg, float* __restrict__ dinv) {
    int n = blockIdx.x * blockDim.x + threadIdx.x;
    if (n >= NN) return;
    dinv[n] = rsqrtf((float)(deg[n] + 1));   // +1 = self loop
}

// out[n] = x[n] * dinv[n]^2  (self-loop term; also zero-initializes the
// scatter target, so no memset needed)
__global__ void init_self(const float* __restrict__ x, const float* __restrict__ dinv,
                          float* __restrict__ out) {
    int tid = blockIdx.x * blockDim.x + threadIdx.x;   // NN*16 threads, float4 each
    if (tid >= NN * 16) return;
    int n = tid >> 4, q = tid & 15;
    float c = dinv[n]; c = c * c;
    float4 v = ((const float4*)(x + (size_t)n * F))[q];
    v.x *= c; v.y *= c; v.z *= c; v.w *= c;
    ((float4*)(out + (size_t)n * F))[q] = v;
}

// out[dst] += x[src] * dinv[src]*dinv[dst]   (atomic scatter, 16 threads/edge)
__global__ void scatter_kernel(const float* __restrict__ x, const int* __restrict__ idx,
                               const int* __restrict__ flag, const float* __restrict__ dinv,
                               float* __restrict__ out) {
    long tid = blockIdx.x * (long)blockDim.x + threadIdx.x;   // NE*16 threads
    if (tid >= (long)NE * 16) return;
    int e = (int)(tid >> 4), q = (int)(tid & 15);
    int is64 = *flag;
    int s = ld_src(idx, e, is64);
    int d = ld_dst(idx, e, is64);
    float c = dinv[s] * dinv[d];
    float4 v = ((const float4*)(x + (size_t)s * F))[q];
    float* o = out + (size_t)d * F + (q << 2);
    atomicAdd(o + 0, v.x * c);
    atomicAdd(o + 1, v.y * c);
    atomicAdd(o + 2, v.z * c);
    atomicAdd(o + 3, v.w * c);
}

// C = relu?(A @ W + b)   A:[NN,64] W:[64,64] b:[64]
// block = 256 threads = 64 cols x 4 row-groups; 32 rows per block.
template <int RELU>
__global__ void gemm64(const float* __restrict__ A, const float* __restrict__ W,
                       const float* __restrict__ b, float* __restrict__ C) {
    __shared__ float Ws[64 * 64];   // 16 KB
    __shared__ float xs[32 * 64];   // 8 KB
    int col = threadIdx.x & 63;
    int rg  = threadIdx.x >> 6;
    for (int i = threadIdx.x; i < 64 * 64 / 4; i += 256)
        ((float4*)Ws)[i] = ((const float4*)W)[i];
    int row0 = blockIdx.x * 32;     // NN % 32 == 0
    for (int i = threadIdx.x; i < 32 * 64 / 4; i += 256)
        ((float4*)xs)[i] = ((const float4*)(A + (size_t)row0 * F))[i];
    __syncthreads();
    float bias = b[col];
    for (int r = rg; r < 32; r += 4) {
        float acc = 0.f;
        #pragma unroll
        for (int k = 0; k < 64; ++k)
            acc = fmaf(xs[r * 64 + k], Ws[k * 64 + col], acc);
        float v = acc + bias;
        if (RELU) v = fmaxf(v, 0.f);
        C[(size_t)(row0 + r) * F + col] = v;
    }
}

extern "C" void kernel_launch(void* const* d_in, const int* in_sizes, int n_in,
                              void* d_out, int out_size, void* d_ws, size_t ws_size,
                              hipStream_t stream) {
    const float* X  = (const float*)d_in[0];
    const int*  idx = (const int*)d_in[1];
    const float* W1 = (const float*)d_in[2];
    const float* b1 = (const float*)d_in[3];
    const float* W2 = (const float*)d_in[4];
    const float* b2 = (const float*)d_in[5];
    const float* W3 = (const float*)d_in[6];
    const float* b3 = (const float*)d_in[7];
    float* out = (float*)d_out;

    char* ws   = (char*)d_ws;
    int*   flag = (int*)(ws + 0);
    int*   deg  = (int*)(ws + 1024);
    float* dinv = (float*)(ws + 321024);
    float* bufA = (float*)(ws + 642048);      // [NN,64] scatter target / gemm input
    float* bufB = (float*)(ws + 21122048);    // [NN,64] gemm output / next source
    // total ws use: ~41.6 MB

    hipMemsetAsync(deg, 0, NN * sizeof(int), stream);
    detect_idx64<<<1, 1, 0, stream>>>(idx, flag);
    deg_kernel<<<(NE + 255) / 256, 256, 0, stream>>>(idx, flag, deg);
    dinv_kernel<<<(NN + 255) / 256, 256, 0, stream>>>(deg, dinv);

    const int initBlocks    = (NN * 16) / 256;       // 5000, exact
    const int scatterBlocks = (NE * 16) / 256;       // 80000, exact
    const int gemmBlocks    = NN / 32;               // 2500, exact

    // layer 1: agg(X) -> bufA ; relu(bufA@W1+b1) -> bufB
    init_self<<<initBlocks, 256, 0, stream>>>(X, dinv, bufA);
    scatter_kernel<<<scatterBlocks, 256, 0, stream>>>(X, idx, flag, dinv, bufA);
    gemm64<1><<<gemmBlocks, 256, 0, stream>>>(bufA, W1, b1, bufB);

    // layer 2
    init_self<<<initBlocks, 256, 0, stream>>>(bufB, dinv, bufA);
    scatter_kernel<<<scatterBlocks, 256, 0, stream>>>(bufB, idx, flag, dinv, bufA);
    gemm64<1><<<gemmBlocks, 256, 0, stream>>>(bufA, W2, b2, bufB);

    // layer 3 (no relu)
    init_self<<<initBlocks, 256, 0, stream>>>(bufB, dinv, bufA);
    scatter_kernel<<<scatterBlocks, 256, 0, stream>>>(bufB, idx, flag, dinv, bufA);
    gemm64<0><<<gemmBlocks, 256, 0, stream>>>(bufA, W3, b3, out);
}

// Round 2
// 715.694 us; speedup vs baseline: 4.8478x; 4.8478x over previous
//
#include <hip/hip_runtime.h>

#define NN 80000
#define NE 1280000
#define F  64

// ---------------------------------------------------------------------------
// edge_index dtype sniffer: reference stores int64; harness docs say int32.
// For little-endian int64 with values < 2^31, every odd 32-bit word is 0.
// Check 1024 of them in parallel.
// ---------------------------------------------------------------------------
__global__ void detect_idx64(const int* __restrict__ idx, int* __restrict__ flag) {
    __shared__ int allzero;
    if (threadIdx.x == 0) allzero = 1;
    __syncthreads();
    if (idx[2 * threadIdx.x + 1] != 0) allzero = 0;
    __syncthreads();
    if (threadIdx.x == 0) *flag = allzero;
}

__device__ __forceinline__ int ld_src(const int* __restrict__ idx, int e, int is64) {
    return is64 ? idx[2 * e] : idx[e];
}
__device__ __forceinline__ int ld_dst(const int* __restrict__ idx, int e, int is64) {
    return is64 ? idx[2 * NE + 2 * e] : idx[NE + e];
}

// deg[d] += 1 per edge (self-loop +1 folded into dinv_kernel)
__global__ void deg_kernel(const int* __restrict__ idx, const int* __restrict__ flag,
                           int* __restrict__ deg) {
    int e = blockIdx.x * blockDim.x + threadIdx.x;
    if (e >= NE) return;
    int is64 = *flag;
    atomicAdd(&deg[ld_dst(idx, e, is64)], 1);
}

__global__ void dinv_kernel(const int* __restrict__ deg, float* __restrict__ dinv) {
    int n = blockIdx.x * blockDim.x + threadIdx.x;
    if (n >= NN) return;
    dinv[n] = rsqrtf((float)(deg[n] + 1));   // +1 = self loop
}

// Exclusive scan of deg -> row_ptr (and cursor copy). Single block, 1024
// threads = 16 waves; wave-shuffle scan, 3 barriers per 1024-chunk.
__global__ __launch_bounds__(1024) void scan_kernel(const int* __restrict__ deg,
                                                    int* __restrict__ row_ptr,
                                                    int* __restrict__ cursor) {
    __shared__ int wsum[16];
    __shared__ int carry_s;
    int tid = threadIdx.x;
    int lane = tid & 63, wv = tid >> 6;
    if (tid == 0) carry_s = 0;
    __syncthreads();
    for (int base = 0; base < NN; base += 1024) {
        int i = base + tid;
        int v = (i < NN) ? deg[i] : 0;
        int incl = v;
        #pragma unroll
        for (int d = 1; d < 64; d <<= 1) {
            int t = __shfl_up(incl, d, 64);
            if (lane >= d) incl += t;
        }
        if (lane == 63) wsum[wv] = incl;
        __syncthreads();
        int woff = 0;
        for (int w = 0; w < wv; ++w) woff += wsum[w];
        int carry = carry_s;
        int excl = carry + woff + incl - v;
        if (i < NN) { row_ptr[i] = excl; cursor[i] = excl; }
        __syncthreads();
        if (tid == 0) {
            int tot = 0;
            for (int w = 0; w < 16; ++w) tot += wsum[w];
            carry_s = carry + tot;
        }
        __syncthreads();
    }
    if (tid == 0) row_ptr[NN] = carry_s;
}

// Counting-sort edges by dst: edata[pos] = (src, coef)
__global__ void sort_kernel(const int* __restrict__ idx, const int* __restrict__ flag,
                            const float* __restrict__ dinv, int* __restrict__ cursor,
                            int2* __restrict__ edata) {
    int e = blockIdx.x * blockDim.x + threadIdx.x;
    if (e >= NE) return;
    int is64 = *flag;
    int s = ld_src(idx, e, is64);
    int d = ld_dst(idx, e, is64);
    float c = dinv[s] * dinv[d];
    int pos = atomicAdd(&cursor[d], 1);
    int2 ed; ed.x = s; ed.y = __float_as_int(c);
    edata[pos] = ed;
}

// Aggregation as CSR gather: one wave per dst node, lane = feature.
// out[n] = x[n]*dinv[n]^2 + sum_{e in in(n)} x[src_e]*coef_e
__global__ void gather_kernel(const float* __restrict__ x, const int2* __restrict__ edata,
                              const int* __restrict__ row_ptr, const float* __restrict__ dinv,
                              float* __restrict__ out) {
    int n = blockIdx.x * 4 + (threadIdx.x >> 6);   // grid = NN/4 exact
    int lane = threadIdx.x & 63;
    float dv = dinv[n];
    float acc = x[(size_t)n * F + lane] * (dv * dv);
    int p1 = row_ptr[n + 1];
    for (int p = row_ptr[n]; p < p1; ++p) {
        int2 ed = edata[p];                         // wave-uniform, L1 broadcast
        acc = fmaf(x[(size_t)ed.x * F + lane], __int_as_float(ed.y), acc);
    }
    out[(size_t)n * F + lane] = acc;
}

// C = relu?(A @ W + b)   A:[NN,64] W:[64,64] b:[64]
template <int RELU>
__global__ void gemm64(const float* __restrict__ A, const float* __restrict__ W,
                       const float* __restrict__ b, float* __restrict__ C) {
    __shared__ float Ws[64 * 64];
    __shared__ float xs[32 * 64];
    int col = threadIdx.x & 63;
    int rg  = threadIdx.x >> 6;
    for (int i = threadIdx.x; i < 64 * 64 / 4; i += 256)
        ((float4*)Ws)[i] = ((const float4*)W)[i];
    int row0 = blockIdx.x * 32;
    for (int i = threadIdx.x; i < 32 * 64 / 4; i += 256)
        ((float4*)xs)[i] = ((const float4*)(A + (size_t)row0 * F))[i];
    __syncthreads();
    float bias = b[col];
    for (int r = rg; r < 32; r += 4) {
        float acc = 0.f;
        #pragma unroll
        for (int k = 0; k < 64; ++k)
            acc = fmaf(xs[r * 64 + k], Ws[k * 64 + col], acc);
        float v = acc + bias;
        if (RELU) v = fmaxf(v, 0.f);
        C[(size_t)(row0 + r) * F + col] = v;
    }
}

extern "C" void kernel_launch(void* const* d_in, const int* in_sizes, int n_in,
                              void* d_out, int out_size, void* d_ws, size_t ws_size,
                              hipStream_t stream) {
    const float* X  = (const float*)d_in[0];
    const int*  idx = (const int*)d_in[1];
    const float* W1 = (const float*)d_in[2];
    const float* b1 = (const float*)d_in[3];
    const float* W2 = (const float*)d_in[4];
    const float* b2 = (const float*)d_in[5];
    const float* W3 = (const float*)d_in[6];
    const float* b3 = (const float*)d_in[7];
    float* out = (float*)d_out;

    char* ws = (char*)d_ws;
    int*   flag    = (int*)(ws + 0);
    int*   deg     = (int*)(ws + 256);
    float* dinv    = (float*)(ws + 320512);
    int*   row_ptr = (int*)(ws + 640512);                // NN+1
    int*   cursor  = (int*)(ws + 960768);
    int2*  edata   = (int2*)(ws + 1280768);              // NE * 8 B
    float* bufA    = (float*)(ws + 11520768);            // [NN,64]
    float* bufB    = (float*)(ws + 32000768);            // [NN,64]
    // total ws use ~52.5 MB

    hipMemsetAsync(deg, 0, NN * sizeof(int), stream);
    detect_idx64<<<1, 1024, 0, stream>>>(idx, flag);
    deg_kernel<<<(NE + 255) / 256, 256, 0, stream>>>(idx, flag, deg);
    dinv_kernel<<<(NN + 255) / 256, 256, 0, stream>>>(deg, dinv);
    scan_kernel<<<1, 1024, 0, stream>>>(deg, row_ptr, cursor);
    sort_kernel<<<(NE + 255) / 256, 256, 0, stream>>>(idx, flag, dinv, cursor, edata);

    const int gatherBlocks = NN / 4;     // 20000, exact
    const int gemmBlocks   = NN / 32;    // 2500, exact

    // layer 1
    gather_kernel<<<gatherBlocks, 256, 0, stream>>>(X, edata, row_ptr, dinv, bufA);
    gemm64<1><<<gemmBlocks, 256, 0, stream>>>(bufA, W1, b1, bufB);
    // layer 2
    gather_kernel<<<gatherBlocks, 256, 0, stream>>>(bufB, edata, row_ptr, dinv, bufA);
    gemm64<1><<<gemmBlocks, 256, 0, stream>>>(bufA, W2, b2, bufB);
    // layer 3 (no relu)
    gather_kernel<<<gatherBlocks, 256, 0, stream>>>(bufB, edata, row_ptr, dinv, bufA);
    gemm64<0><<<gemmBlocks, 256, 0, stream>>>(bufA, W3, b3, out);
}

// Round 3
// 432.000 us; speedup vs baseline: 8.0313x; 1.6567x over previous
//
#include <hip/hip_runtime.h>

#define NN 80000
#define NE 1280000
#define F  64
#define NBLK ((NN + 1023) / 1024)   // 79 scan blocks

// ---------------------------------------------------------------------------
// edge_index dtype sniffer: int64 (reference) vs int32 (harness doc).
// ---------------------------------------------------------------------------
__global__ void detect_idx64(const int* __restrict__ idx, int* __restrict__ flag) {
    __shared__ int allzero;
    if (threadIdx.x == 0) allzero = 1;
    __syncthreads();
    if (idx[2 * threadIdx.x + 1] != 0) allzero = 0;
    __syncthreads();
    if (threadIdx.x == 0) *flag = allzero;
}

__device__ __forceinline__ int ld_src(const int* __restrict__ idx, int e, int is64) {
    return is64 ? idx[2 * e] : idx[e];
}
__device__ __forceinline__ int ld_dst(const int* __restrict__ idx, int e, int is64) {
    return is64 ? idx[2 * NE + 2 * e] : idx[NE + e];
}

__global__ void deg_kernel(const int* __restrict__ idx, const int* __restrict__ flag,
                           int* __restrict__ deg) {
    int e = blockIdx.x * blockDim.x + threadIdx.x;
    if (e >= NE) return;
    int is64 = *flag;
    atomicAdd(&deg[ld_dst(idx, e, is64)], 1);
}

__global__ void dinv_kernel(const int* __restrict__ deg, float* __restrict__ dinv) {
    int n = blockIdx.x * blockDim.x + threadIdx.x;
    if (n >= NN) return;
    dinv[n] = rsqrtf((float)(deg[n] + 1));   // +1 = self loop
}

// ---- 3-phase parallel exclusive scan of deg -> row_ptr ----
__global__ __launch_bounds__(1024) void scan_partial(const int* __restrict__ deg,
                                                     int* __restrict__ row_ptr,
                                                     int* __restrict__ bsum) {
    __shared__ int wsum[16];
    int i = blockIdx.x * 1024 + threadIdx.x;
    int lane = threadIdx.x & 63, wv = threadIdx.x >> 6;
    int v = (i < NN) ? deg[i] : 0;
    int incl = v;
    #pragma unroll
    for (int d = 1; d < 64; d <<= 1) {
        int t = __shfl_up(incl, d, 64);
        if (lane >= d) incl += t;
    }
    if (lane == 63) wsum[wv] = incl;
    __syncthreads();
    int woff = 0;
    for (int w = 0; w < wv; ++w) woff += wsum[w];
    if (i < NN) row_ptr[i] = woff + incl - v;       // local exclusive
    if (threadIdx.x == 1023) bsum[blockIdx.x] = woff + incl;
}

__global__ void scan_bsum(int* __restrict__ bsum) {   // 1 wave, 64 threads
    int lane = threadIdx.x;
    int carry = 0;
    for (int base = 0; base < NBLK; base += 64) {
        int v = (base + lane < NBLK) ? bsum[base + lane] : 0;
        int incl = v;
        #pragma unroll
        for (int d = 1; d < 64; d <<= 1) {
            int t = __shfl_up(incl, d, 64);
            if (lane >= d) incl += t;
        }
        if (base + lane < NBLK) bsum[base + lane] = carry + incl - v;
        carry += __shfl(incl, 63);
    }
}

__global__ void scan_apply(const int* __restrict__ bsum, int* __restrict__ row_ptr,
                           int* __restrict__ cursor) {
    int i = blockIdx.x * 256 + threadIdx.x;
    if (i >= NN) {
        if (i == NN) row_ptr[NN] = NE;
        return;
    }
    int v = row_ptr[i] + bsum[i >> 10];
    row_ptr[i] = v;
    cursor[i] = v;
}

// Counting-sort edges by dst: edata[pos] = (src, coef)
__global__ void sort_kernel(const int* __restrict__ idx, const int* __restrict__ flag,
                            const float* __restrict__ dinv, int* __restrict__ cursor,
                            int2* __restrict__ edata) {
    int e = blockIdx.x * blockDim.x + threadIdx.x;
    if (e >= NE) return;
    int is64 = *flag;
    int s = ld_src(idx, e, is64);
    int d = ld_dst(idx, e, is64);
    float c = dinv[s] * dinv[d];
    int pos = atomicAdd(&cursor[d], 1);
    int2 ed; ed.x = s; ed.y = __float_as_int(c);
    edata[pos] = ed;
}

// CSR gather, one wave per dst node, lane = feature, 8-way ILP unroll.
__global__ __launch_bounds__(256) void gather_kernel(const float* __restrict__ x,
        const int2* __restrict__ edata, const int* __restrict__ row_ptr,
        const float* __restrict__ dinv, float* __restrict__ out) {
    int n = blockIdx.x * 4 + (threadIdx.x >> 6);   // grid = NN/4 exact
    int lane = threadIdx.x & 63;
    float dv = dinv[n];
    float acc = x[(size_t)n * F + lane] * (dv * dv);
    int p0 = row_ptr[n], p1 = row_ptr[n + 1];
    for (int p = p0; p < p1; p += 8) {
        int2 e[8];
        float c[8];
        #pragma unroll
        for (int j = 0; j < 8; ++j) {
            int q = p + j;
            int qi = q < p1 ? q : p1 - 1;          // clamp (p1>p0 here)
            e[j] = edata[qi];
            c[j] = (q < p1) ? __int_as_float(e[j].y) : 0.f;
        }
        float v[8];
        #pragma unroll
        for (int j = 0; j < 8; ++j) v[j] = x[(size_t)e[j].x * F + lane];
        #pragma unroll
        for (int j = 0; j < 8; ++j) acc = fmaf(v[j], c[j], acc);
    }
    out[(size_t)n * F + lane] = acc;
}

// C = relu?(A @ W + b); 8 rows/thread register accumulation.
template <int RELU>
__global__ __launch_bounds__(256) void gemm64(const float* __restrict__ A,
        const float* __restrict__ W, const float* __restrict__ b, float* __restrict__ C) {
    __shared__ float Ws[64 * 64];
    __shared__ float xs[32 * 64];
    int col = threadIdx.x & 63;
    int rg  = threadIdx.x >> 6;          // row group: rows rg*8 .. rg*8+7
    for (int i = threadIdx.x; i < 64 * 64 / 4; i += 256)
        ((float4*)Ws)[i] = ((const float4*)W)[i];
    int row0 = blockIdx.x * 32;
    for (int i = threadIdx.x; i < 32 * 64 / 4; i += 256)
        ((float4*)xs)[i] = ((const float4*)(A + (size_t)row0 * F))[i];
    __syncthreads();
    float acc[8];
    #pragma unroll
    for (int r = 0; r < 8; ++r) acc[r] = 0.f;
    for (int k = 0; k < 64; ++k) {
        float wk = Ws[k * 64 + col];
        #pragma unroll
        for (int r = 0; r < 8; ++r)
            acc[r] = fmaf(xs[(rg * 8 + r) * 64 + k], wk, acc[r]);
    }
    float bias = b[col];
    #pragma unroll
    for (int r = 0; r < 8; ++r) {
        float v = acc[r] + bias;
        if (RELU) v = fmaxf(v, 0.f);
        C[(size_t)(row0 + rg * 8 + r) * F + col] = v;
    }
}

extern "C" void kernel_launch(void* const* d_in, const int* in_sizes, int n_in,
                              void* d_out, int out_size, void* d_ws, size_t ws_size,
                              hipStream_t stream) {
    const float* X  = (const float*)d_in[0];
    const int*  idx = (const int*)d_in[1];
    const float* W1 = (const float*)d_in[2];
    const float* b1 = (const float*)d_in[3];
    const float* W2 = (const float*)d_in[4];
    const float* b2 = (const float*)d_in[5];
    const float* W3 = (const float*)d_in[6];
    const float* b3 = (const float*)d_in[7];
    float* out = (float*)d_out;

    char* ws = (char*)d_ws;
    int*   flag    = (int*)(ws + 0);
    int*   bsum    = (int*)(ws + 256);                   // NBLK ints
    int*   deg     = (int*)(ws + 1024);
    float* dinv    = (float*)(ws + 321024);
    int*   row_ptr = (int*)(ws + 641024);                // NN+1
    int*   cursor  = (int*)(ws + 961280);
    int2*  edata   = (int2*)(ws + 1281280);              // NE * 8 B
    float* bufA    = (float*)(ws + 11521280);            // [NN,64]
    float* bufB    = (float*)(ws + 32001280);            // [NN,64]

    hipMemsetAsync(deg, 0, NN * sizeof(int), stream);
    detect_idx64<<<1, 1024, 0, stream>>>(idx, flag);
    deg_kernel<<<(NE + 255) / 256, 256, 0, stream>>>(idx, flag, deg);
    dinv_kernel<<<(NN + 255) / 256, 256, 0, stream>>>(deg, dinv);
    scan_partial<<<NBLK, 1024, 0, stream>>>(deg, row_ptr, bsum);
    scan_bsum<<<1, 64, 0, stream>>>(bsum);
    scan_apply<<<(NN + 256) / 256, 256, 0, stream>>>(bsum, row_ptr, cursor);
    sort_kernel<<<(NE + 255) / 256, 256, 0, stream>>>(idx, flag, dinv, cursor, edata);

    const int gatherBlocks = NN / 4;     // 20000
    const int gemmBlocks   = NN / 32;    // 2500

    gather_kernel<<<gatherBlocks, 256, 0, stream>>>(X, edata, row_ptr, dinv, bufA);
    gemm64<1><<<gemmBlocks, 256, 0, stream>>>(bufA, W1, b1, bufB);

    gather_kernel<<<gatherBlocks, 256, 0, stream>>>(bufB, edata, row_ptr, dinv, bufA);
    gemm64<1><<<gemmBlocks, 256, 0, stream>>>(bufA, W2, b2, bufB);

    gather_kernel<<<gatherBlocks, 256, 0, stream>>>(bufB, edata, row_ptr, dinv, bufA);
    gemm64<0><<<gemmBlocks, 256, 0, stream>>>(bufA, W3, b3, out);
}